// Round 8
// baseline (26.896 us; speedup 1.0000x reference)
//
#include <hip/hip_runtime.h>
#include <math.h>

#define NN 20
#define ED 4
#define XROW 160
#define NC 80
#define NKT 5
#define NNT 5
#define FRAG_BYTES (NKT * NNT * 64 * 16)     // 25600
#define BIAS_OFF   FRAG_BYTES                // 25600
#define LIN_OFF    (BIAS_OFF + NC * 4)       // 25920
#define CONS_BYTES (LIN_OFF + 16)            // 25936
#define CONS_U4    (CONS_BYTES / 16)         // 1621
#define THREADS 512
#define STH 640
#define ROWS_PER_WAVE 16
#define ROWS_PER_BLOCK 128                   // 8 waves * 16 rows

typedef __attribute__((ext_vector_type(8))) _Float16 half8;
typedef __attribute__((ext_vector_type(4))) float f32x4;
typedef __attribute__((ext_vector_type(4))) unsigned uint4v;

static __device__ __forceinline__ half8 cvt8(float4 a, float4 b) {
    uint4v u = (uint4v){
        __builtin_bit_cast(unsigned, __builtin_amdgcn_cvt_pkrtz(a.x, a.y)),
        __builtin_bit_cast(unsigned, __builtin_amdgcn_cvt_pkrtz(a.z, a.w)),
        __builtin_bit_cast(unsigned, __builtin_amdgcn_cvt_pkrtz(b.x, b.y)),
        __builtin_bit_cast(unsigned, __builtin_amdgcn_cvt_pkrtz(b.z, b.w))};
    return __builtin_bit_cast(half8, u);
}

// quad_perm DPP: xor1 = [1,0,3,2] = 0xB1 ; xor2 = [2,3,0,1] = 0x4E
static __device__ __forceinline__ float dpp_xor1(float v) {
    return __builtin_bit_cast(float,
        __builtin_amdgcn_mov_dpp(__builtin_bit_cast(int, v), 0xB1, 0xF, 0xF, true));
}
static __device__ __forceinline__ float dpp_xor2(float v) {
    return __builtin_bit_cast(float,
        __builtin_amdgcn_mov_dpp(__builtin_bit_cast(int, v), 0x4E, 0xF, 0xF, true));
}

// ---------------- setup: fold everything into fp16 B-frag table in d_ws ------
__global__ __launch_bounds__(STH) void rgcn_setup(
        const float* __restrict__ e,
        const float* __restrict__ gate_w,
        const float* __restrict__ gate_b,
        const float* __restrict__ upd_w,
        const float* __restrict__ upd_b,
        const float* __restrict__ lin_w,
        const float* __restrict__ lin_b,
        char* __restrict__ ws) {
    __shared__ float el[80];
    __shared__ float sA[400];
    __shared__ float wself[640];
    __shared__ float wagg[640];
    const int t = threadIdx.x;
    const int l = t & 63;
    const int w = t >> 6;

    // --- prefetch ALL global weight reads before the first barrier (no dep on e) ---
    const int c = t >> 3, i = t & 7;          // t in [0,640): one (c,i) per thread
    const int n_ = c >> 2, ro = c & 3;
    float p0[4], p1[4];
    {
        const float* b0;
        const float* b1;
        int st;
        if (ro < 2) { b0 = gate_w + i * 4 + 2 + ro; b1 = b0 + 40; st = 80; }
        else        { b0 = upd_w  + i * 2 + ro - 2; b1 = b0 + 20; st = 40; }
        #pragma unroll
        for (int d = 0; d < ED; ++d) { p0[d] = b0[d * st]; p1[d] = b1[d * st]; }
    }
    float pb[4];
    if (t < NC) {
        int rb = t & 3;
        #pragma unroll
        for (int d = 0; d < ED; ++d)
            pb[d] = (rb < 2) ? gate_b[d * 4 + 2 + rb] : upd_b[d * 2 + rb - 2];
    }
    if (t < 80) el[t] = e[t];
    float* wbias = (float*)(ws + BIAS_OFF);
    float* wlin  = (float*)(ws + LIN_OFF);
    if (t == 0) { wlin[0] = lin_w[0]; wlin[1] = lin_w[1]; wlin[2] = lin_b[0]; wlin[3] = 0.f; }
    __syncthreads();

    // --- scores + folds + bias (all reads from LDS/regs now) ---
    if (t < 400) {
        int nn = t / 20, mm = t - (t / 20) * 20;
        float d = 0.f;
        for (int j = 0; j < ED; ++j) d += el[nn * ED + j] * el[mm * ED + j];
        sA[t] = fmaxf(d, 0.f);
    }
    {
        float vs = 0.f, va = 0.f;
        #pragma unroll
        for (int d = 0; d < ED; ++d) {
            float ev = el[n_ * ED + d];
            vs += ev * p0[d];
            va += ev * p1[d];
        }
        wself[t] = vs;
        wagg[t]  = va;
    }
    if (t < NC) {
        float b = 0.f;
        #pragma unroll
        for (int d = 0; d < ED; ++d) b += el[(t >> 2) * ED + d] * pb[d];
        wbias[t] = b;
    }
    __syncthreads();

    // --- row softmax in place ---
    if (t < NN) {
        float mx = -1e30f;
        for (int m = 0; m < NN; ++m) mx = fmaxf(mx, sA[t * 20 + m]);
        float ex[NN]; float sum = 0.f;
        for (int m = 0; m < NN; ++m) { ex[m] = __expf(sA[t * 20 + m] - mx); sum += ex[m]; }
        float inv = 1.f / sum;
        for (int m = 0; m < NN; ++m) sA[t * 20 + m] = ex[m] * inv;
    }
    __syncthreads();

    // --- build fp16 B-fragments ---
    half8* frag = (half8*)ws;
    for (int tile = w; tile < NKT * NNT; tile += (STH / 64)) {
        int kt = tile / 5, nt = tile - kt * 5;
        int cc = nt * 16 + (l & 15);
        int nn = cc >> 2;
        int mm = kt * 4 + (l >> 4);
        float anm = sA[nn * 20 + mm];
        float4 wg0 = *(const float4*)&wagg[cc * 8];
        float4 wg1 = *(const float4*)&wagg[cc * 8 + 4];
        float v0 = anm * wg0.x, v1 = anm * wg0.y, v2 = anm * wg0.z, v3 = anm * wg0.w;
        float v4 = anm * wg1.x, v5 = anm * wg1.y, v6 = anm * wg1.z, v7 = anm * wg1.w;
        if (nn == mm) {
            float4 ws0 = *(const float4*)&wself[cc * 8];
            float4 ws1 = *(const float4*)&wself[cc * 8 + 4];
            v0 += ws0.x; v1 += ws0.y; v2 += ws0.z; v3 += ws0.w;
            v4 += ws1.x; v5 += ws1.y; v6 += ws1.z; v7 += ws1.w;
        }
        half8 hv;
        hv[0] = (_Float16)v0; hv[1] = (_Float16)v1; hv[2] = (_Float16)v2; hv[3] = (_Float16)v3;
        hv[4] = (_Float16)v4; hv[5] = (_Float16)v5; hv[6] = (_Float16)v6; hv[7] = (_Float16)v7;
        frag[tile * 64 + l] = hv;
    }
}

// ---------------- main: burst-load x, fp16 MFMA, DPP epilogue ---------------
__global__ __launch_bounds__(THREADS, 6) void rgcn_main(
        const float* __restrict__ x,
        const char* __restrict__ cons,
        float* __restrict__ y) {
    __shared__ __align__(16) char smem[CONS_BYTES];
    const int t = threadIdx.x;
    const int l = t & 63;
    const int w = t >> 6;

    // full x burst for this wave's 16 rows: 10 float4 in flight before any compute
    const size_t row0 = (size_t)blockIdx.x * ROWS_PER_BLOCK + (size_t)w * ROWS_PER_WAVE;
    const float* xp = x + (row0 + (l & 15)) * XROW + ((l >> 4) << 3);
    float4 xa0 = *(const float4*)(xp);       float4 xb0 = *(const float4*)(xp + 4);
    float4 xa1 = *(const float4*)(xp + 32);  float4 xb1 = *(const float4*)(xp + 36);
    float4 xa2 = *(const float4*)(xp + 64);  float4 xb2 = *(const float4*)(xp + 68);
    float4 xa3 = *(const float4*)(xp + 96);  float4 xb3 = *(const float4*)(xp + 100);
    float4 xa4 = *(const float4*)(xp + 128); float4 xb4 = *(const float4*)(xp + 132);

    // cons table -> LDS (26 KB, coalesced) — overlaps x-burst latency
    {
        const uint4v* src = (const uint4v*)cons;
        uint4v* dst = (uint4v*)smem;
        #pragma unroll
        for (int i = t; i < CONS_U4; i += THREADS) dst[i] = src[i];
    }
    __syncthreads();

    const half8* frag = (const half8*)smem;
    const float* sbias = (const float*)(smem + BIAS_OFF);
    const float* slin  = (const float*)(smem + LIN_OFF);

    // bias folded into accumulator init
    f32x4 acc[NNT];
    #pragma unroll
    for (int nt = 0; nt < NNT; ++nt) {
        float b = sbias[nt * 16 + (l & 15)];
        acc[nt] = (f32x4){b, b, b, b};
    }

    #define STEP(XA, XB, KT)                                                        \
    {                                                                               \
        half8 a = cvt8(XA, XB);                                                     \
        _Pragma("unroll")                                                           \
        for (int nt = 0; nt < NNT; ++nt) {                                          \
            half8 bh = frag[((KT) * NNT + nt) * 64 + l];                            \
            acc[nt] = __builtin_amdgcn_mfma_f32_16x16x32_f16(a, bh, acc[nt], 0, 0, 0); \
        }                                                                           \
    }
    STEP(xa0, xb0, 0)
    STEP(xa1, xb1, 1)
    STEP(xa2, xb2, 2)
    STEP(xa3, xb3, 3)
    STEP(xa4, xb4, 4)
    #undef STEP

    // ---- DPP epilogue: combine ro 0..3 within each lane-quad, no barriers ----
    // lane holds c = nt*16 + (l&15) = 4n+ro, rows (l>>4)*4 + q
    const float lw0 = slin[0], lw1 = slin[1], lb = slin[2];
    const int ro = l & 3;
    const bool isR = ro < 2;
    const float myw = (ro & 1) ? lw1 : lw0;
    const size_t rowb = row0 + ((l >> 4) << 2) + ro;   // the row this lane stores (q == ro)

    #pragma unroll
    for (int nt = 0; nt < NNT; ++nt) {
        const int n = nt * 4 + ((l & 15) >> 2);
        float ysel = 0.f;
        #pragma unroll
        for (int q = 0; q < 4; ++q) {
            float pre = acc[nt][q];
            float term;
            if (isR) {
                // 1 - sigmoid(pre) = 1/(1+exp(pre))
                term = __builtin_amdgcn_rcpf(1.f + __expf(pre));
            } else {
                // tanh(pre)
                term = 1.f - 2.f * __builtin_amdgcn_rcpf(__expf(2.f * pre) + 1.f);
            }
            float other = dpp_xor2(term);     // pair (1-sig) with tanh
            float h = term * other;           // lanes 0,2: h0 ; lanes 1,3: h1
            float s = fmaxf(h, 0.f) * myw;
            float yq = s + dpp_xor1(s) + lb;  // all 4 lanes: final y(row q, n)
            if (q == ro) ysel = yq;
        }
        y[rowb * NN + n] = ysel;
    }
}

extern "C" void kernel_launch(void* const* d_in, const int* in_sizes, int n_in,
                              void* d_out, int out_size, void* d_ws, size_t ws_size,
                              hipStream_t stream) {
    const float* x      = (const float*)d_in[0];
    const float* e      = (const float*)d_in[1];
    const float* gate_w = (const float*)d_in[2];
    const float* gate_b = (const float*)d_in[3];
    const float* upd_w  = (const float*)d_in[4];
    const float* upd_b  = (const float*)d_in[5];
    const float* lin_w  = (const float*)d_in[6];
    const float* lin_b  = (const float*)d_in[7];
    char* cons = (char*)d_ws;
    float* y   = (float*)d_out;

    const int Bn = in_sizes[0] / XROW;           // 131072
    const int nblocks = Bn / ROWS_PER_BLOCK;     // 1024

    rgcn_setup<<<1, STH, 0, stream>>>(e, gate_w, gate_b, upd_w, upd_b,
                                      lin_w, lin_b, cons);
    rgcn_main<<<nblocks, THREADS, 0, stream>>>(x, cons, y);
}

// Round 9
// 26.547 us; speedup vs baseline: 1.0132x; 1.0132x over previous
//
#include <hip/hip_runtime.h>
#include <math.h>

#define NN 20
#define ED 4
#define XROW 160
#define NC 80
#define NKT 5
#define NNT 5
#define FRAG_BYTES (NKT * NNT * 64 * 16)     // 25600
#define THREADS 512
#define ROWS_PER_WAVE 16
#define ROWS_PER_BLOCK 128                   // 8 waves * 16 rows

typedef __attribute__((ext_vector_type(8))) _Float16 half8;
typedef __attribute__((ext_vector_type(4))) float f32x4;
typedef __attribute__((ext_vector_type(4))) unsigned uint4v;

static __device__ __forceinline__ half8 cvt8(float4 a, float4 b) {
    uint4v u = (uint4v){
        __builtin_bit_cast(unsigned, __builtin_amdgcn_cvt_pkrtz(a.x, a.y)),
        __builtin_bit_cast(unsigned, __builtin_amdgcn_cvt_pkrtz(a.z, a.w)),
        __builtin_bit_cast(unsigned, __builtin_amdgcn_cvt_pkrtz(b.x, b.y)),
        __builtin_bit_cast(unsigned, __builtin_amdgcn_cvt_pkrtz(b.z, b.w))};
    return __builtin_bit_cast(half8, u);
}

// quad_perm DPP: xor1 = [1,0,3,2] = 0xB1 ; xor2 = [2,3,0,1] = 0x4E
static __device__ __forceinline__ float dpp_xor1(float v) {
    return __builtin_bit_cast(float,
        __builtin_amdgcn_mov_dpp(__builtin_bit_cast(int, v), 0xB1, 0xF, 0xF, true));
}
static __device__ __forceinline__ float dpp_xor2(float v) {
    return __builtin_bit_cast(float,
        __builtin_amdgcn_mov_dpp(__builtin_bit_cast(int, v), 0x4E, 0xF, 0xF, true));
}

__global__ __launch_bounds__(THREADS, 4) void rgcn_fused(
        const float* __restrict__ x,
        const float* __restrict__ e,
        const float* __restrict__ gate_w,
        const float* __restrict__ gate_b,
        const float* __restrict__ upd_w,
        const float* __restrict__ upd_b,
        const float* __restrict__ lin_w,
        const float* __restrict__ lin_b,
        float* __restrict__ y) {
    __shared__ __align__(16) char fragmem[FRAG_BYTES];   // fp16 B-fragments
    __shared__ float sbias[NC];
    __shared__ float el[80];
    __shared__ float sA[400];
    __shared__ float wself[640];
    __shared__ float wagg[640];

    const int t = threadIdx.x;
    const int l = t & 63;
    const int w = t >> 6;

    // ---- x burst FIRST: 10 float4 in flight; setup latency hides under it ----
    const size_t row0 = (size_t)blockIdx.x * ROWS_PER_BLOCK + (size_t)w * ROWS_PER_WAVE;
    const float* xp = x + (row0 + (l & 15)) * XROW + ((l >> 4) << 3);
    float4 xa0 = *(const float4*)(xp);       float4 xb0 = *(const float4*)(xp + 4);
    float4 xa1 = *(const float4*)(xp + 32);  float4 xb1 = *(const float4*)(xp + 36);
    float4 xa2 = *(const float4*)(xp + 64);  float4 xb2 = *(const float4*)(xp + 68);
    float4 xa3 = *(const float4*)(xp + 96);  float4 xb3 = *(const float4*)(xp + 100);
    float4 xa4 = *(const float4*)(xp + 128); float4 xb4 = *(const float4*)(xp + 132);

    // ---- setup phase (per-block, redundant; ~0.9 µs, hidden under burst) ----
    if (t < NN * ED) el[t] = e[t];
    __syncthreads();

    if (t < 400) {
        int nn = t / 20, mm = t - (t / 20) * 20;
        float d = 0.f;
        #pragma unroll
        for (int j = 0; j < ED; ++j) d += el[nn * ED + j] * el[mm * ED + j];
        sA[t] = fmaxf(d, 0.f);
    }
    #pragma unroll
    for (int idx = t; idx < 1280; idx += THREADS) {
        int sel = idx >= 640;              // 0: self (k=0), 1: agg (k=1)
        int rem = sel ? idx - 640 : idx;
        int c = rem >> 3, i = rem & 7;
        int n = c >> 2, ro = c & 3;
        float v = 0.f;
        if (ro < 2) {
            int o = 2 + ro;                // R columns of gate_w (4,2,10,4)
            #pragma unroll
            for (int d = 0; d < ED; ++d) v += el[n * ED + d] * gate_w[d * 80 + sel * 40 + i * 4 + o];
        } else {
            int o = ro - 2;                // upd_w (4,2,10,2)
            #pragma unroll
            for (int d = 0; d < ED; ++d) v += el[n * ED + d] * upd_w[d * 40 + sel * 20 + i * 2 + o];
        }
        (sel ? wagg : wself)[rem] = v;
    }
    if (t < NC) {
        int n = t >> 2, ro = t & 3;
        float b = 0.f;
        #pragma unroll
        for (int d = 0; d < ED; ++d)
            b += el[n * ED + d] * (ro < 2 ? gate_b[d * 4 + 2 + ro] : upd_b[d * 2 + ro - 2]);
        sbias[t] = b;
    }
    __syncthreads();

    if (t < NN) {                          // row softmax in place (serial-20, ~0.3 µs)
        float mx = -1e30f;
        for (int m = 0; m < NN; ++m) mx = fmaxf(mx, sA[t * 20 + m]);
        float ex[NN]; float sum = 0.f;
        for (int m = 0; m < NN; ++m) { ex[m] = __expf(sA[t * 20 + m] - mx); sum += ex[m]; }
        float inv = 1.f / sum;
        for (int m = 0; m < NN; ++m) sA[t * 20 + m] = ex[m] * inv;
    }
    __syncthreads();

    // ---- build fp16 B-fragments in LDS ----
    {
        half8* frag = (half8*)fragmem;
        for (int tile = w; tile < NKT * NNT; tile += 8) {
            int kt = tile / 5, nt = tile - kt * 5;
            int cc = nt * 16 + (l & 15);
            int nn = cc >> 2;
            int mm = kt * 4 + (l >> 4);
            float anm = sA[nn * 20 + mm];
            float4 wg0 = *(const float4*)&wagg[cc * 8];
            float4 wg1 = *(const float4*)&wagg[cc * 8 + 4];
            float v0 = anm * wg0.x, v1 = anm * wg0.y, v2 = anm * wg0.z, v3 = anm * wg0.w;
            float v4 = anm * wg1.x, v5 = anm * wg1.y, v6 = anm * wg1.z, v7 = anm * wg1.w;
            if (nn == mm) {
                float4 ws0 = *(const float4*)&wself[cc * 8];
                float4 ws1 = *(const float4*)&wself[cc * 8 + 4];
                v0 += ws0.x; v1 += ws0.y; v2 += ws0.z; v3 += ws0.w;
                v4 += ws1.x; v5 += ws1.y; v6 += ws1.z; v7 += ws1.w;
            }
            half8 hv;
            hv[0] = (_Float16)v0; hv[1] = (_Float16)v1; hv[2] = (_Float16)v2; hv[3] = (_Float16)v3;
            hv[4] = (_Float16)v4; hv[5] = (_Float16)v5; hv[6] = (_Float16)v6; hv[7] = (_Float16)v7;
            frag[tile * 64 + l] = hv;
        }
    }
    __syncthreads();

    // ---- MFMA: bias folded into accumulator init ----
    const half8* frag = (const half8*)fragmem;
    f32x4 acc[NNT];
    #pragma unroll
    for (int nt = 0; nt < NNT; ++nt) {
        float b = sbias[nt * 16 + (l & 15)];
        acc[nt] = (f32x4){b, b, b, b};
    }

    #define STEP(XA, XB, KT)                                                        \
    {                                                                               \
        half8 a = cvt8(XA, XB);                                                     \
        _Pragma("unroll")                                                           \
        for (int nt = 0; nt < NNT; ++nt) {                                          \
            half8 bh = frag[((KT) * NNT + nt) * 64 + l];                            \
            acc[nt] = __builtin_amdgcn_mfma_f32_16x16x32_f16(a, bh, acc[nt], 0, 0, 0); \
        }                                                                           \
    }
    STEP(xa0, xb0, 0)
    STEP(xa1, xb1, 1)
    STEP(xa2, xb2, 2)
    STEP(xa3, xb3, 3)
    STEP(xa4, xb4, 4)
    #undef STEP

    // ---- DPP epilogue: combine ro 0..3 within each lane-quad, no barriers ----
    const float lw0 = lin_w[0], lw1 = lin_w[1], lb = lin_b[0];   // uniform s_loads, L2-hot
    const int ro = l & 3;
    const bool isR = ro < 2;
    const float myw = (ro & 1) ? lw1 : lw0;
    const size_t rowb = row0 + ((l >> 4) << 2) + ro;   // the row this lane stores (q == ro)

    #pragma unroll
    for (int nt = 0; nt < NNT; ++nt) {
        const int n = nt * 4 + ((l & 15) >> 2);
        float ysel = 0.f;
        #pragma unroll
        for (int q = 0; q < 4; ++q) {
            float pre = acc[nt][q];
            float term;
            if (isR) {
                term = __builtin_amdgcn_rcpf(1.f + __expf(pre));              // 1-sigmoid
            } else {
                term = 1.f - 2.f * __builtin_amdgcn_rcpf(__expf(2.f * pre) + 1.f); // tanh
            }
            float other = dpp_xor2(term);
            float h = term * other;           // lanes 0,2: h0 ; lanes 1,3: h1
            float s = fmaxf(h, 0.f) * myw;
            float yq = s + dpp_xor1(s) + lb;
            if (q == ro) ysel = yq;
        }
        y[rowb * NN + n] = ysel;
    }
}

extern "C" void kernel_launch(void* const* d_in, const int* in_sizes, int n_in,
                              void* d_out, int out_size, void* d_ws, size_t ws_size,
                              hipStream_t stream) {
    const float* x      = (const float*)d_in[0];
    const float* e      = (const float*)d_in[1];
    const float* gate_w = (const float*)d_in[2];
    const float* gate_b = (const float*)d_in[3];
    const float* upd_w  = (const float*)d_in[4];
    const float* upd_b  = (const float*)d_in[5];
    const float* lin_w  = (const float*)d_in[6];
    const float* lin_b  = (const float*)d_in[7];
    float* y = (float*)d_out;

    const int Bn = in_sizes[0] / XROW;           // 131072
    const int nblocks = Bn / ROWS_PER_BLOCK;     // 1024

    rgcn_fused<<<nblocks, THREADS, 0, stream>>>(x, e, gate_w, gate_b,
                                                upd_w, upd_b, lin_w, lin_b, y);
}

// Round 10
// 24.711 us; speedup vs baseline: 1.0884x; 1.0743x over previous
//
#include <hip/hip_runtime.h>
#include <math.h>

#define NN 20
#define ED 4
#define XROW 160
#define NC 80
#define NKT 5
#define NNT 5
#define FRAG_BYTES (NKT * NNT * 64 * 16)     // 25600
#define THREADS 512
#define ROWS_PER_WAVE 16
#define ROWS_PER_BLOCK 128                   // 8 waves * 16 rows
#define TPB 2                                // tiles per persistent block

typedef __attribute__((ext_vector_type(8))) _Float16 half8;
typedef __attribute__((ext_vector_type(4))) float f32x4;
typedef __attribute__((ext_vector_type(4))) unsigned uint4v;

static __device__ __forceinline__ half8 cvt8(float4 a, float4 b) {
    uint4v u = (uint4v){
        __builtin_bit_cast(unsigned, __builtin_amdgcn_cvt_pkrtz(a.x, a.y)),
        __builtin_bit_cast(unsigned, __builtin_amdgcn_cvt_pkrtz(a.z, a.w)),
        __builtin_bit_cast(unsigned, __builtin_amdgcn_cvt_pkrtz(b.x, b.y)),
        __builtin_bit_cast(unsigned, __builtin_amdgcn_cvt_pkrtz(b.z, b.w))};
    return __builtin_bit_cast(half8, u);
}

// quad_perm DPP: xor1 = [1,0,3,2] = 0xB1 ; xor2 = [2,3,0,1] = 0x4E
static __device__ __forceinline__ float dpp_xor1(float v) {
    return __builtin_bit_cast(float,
        __builtin_amdgcn_mov_dpp(__builtin_bit_cast(int, v), 0xB1, 0xF, 0xF, true));
}
static __device__ __forceinline__ float dpp_xor2(float v) {
    return __builtin_bit_cast(float,
        __builtin_amdgcn_mov_dpp(__builtin_bit_cast(int, v), 0x4E, 0xF, 0xF, true));
}

__global__ __launch_bounds__(THREADS, 4) void rgcn_fused(
        const float* __restrict__ x,
        const float* __restrict__ e,
        const float* __restrict__ gate_w,
        const float* __restrict__ gate_b,
        const float* __restrict__ upd_w,
        const float* __restrict__ upd_b,
        const float* __restrict__ lin_w,
        const float* __restrict__ lin_b,
        float* __restrict__ y) {
    __shared__ __align__(16) char fragmem[FRAG_BYTES];
    __shared__ float sbias[NC];
    __shared__ float el[80];
    __shared__ float sA[400];
    __shared__ float wself[640];
    __shared__ float wagg[640];

    const int t = threadIdx.x;
    const int l = t & 63;
    const int w = t >> 6;

    // rows for this wave's two tiles
    const size_t rowA = ((size_t)blockIdx.x * TPB + 0) * ROWS_PER_BLOCK + (size_t)w * ROWS_PER_WAVE;
    const size_t rowB = ((size_t)blockIdx.x * TPB + 1) * ROWS_PER_BLOCK + (size_t)w * ROWS_PER_WAVE;
    const float* xpA = x + (rowA + (l & 15)) * XROW + ((l >> 4) << 3);
    const float* xpB = x + (rowB + (l & 15)) * XROW + ((l >> 4) << 3);

    // ---- burst A: issued first, latency hidden under setup ----
    float4 Aa0 = *(const float4*)(xpA);       float4 Ab0 = *(const float4*)(xpA + 4);
    float4 Aa1 = *(const float4*)(xpA + 32);  float4 Ab1 = *(const float4*)(xpA + 36);
    float4 Aa2 = *(const float4*)(xpA + 64);  float4 Ab2 = *(const float4*)(xpA + 68);
    float4 Aa3 = *(const float4*)(xpA + 96);  float4 Ab3 = *(const float4*)(xpA + 100);
    float4 Aa4 = *(const float4*)(xpA + 128); float4 Ab4 = *(const float4*)(xpA + 132);

    // ---- setup (once per block, amortized over 2 tiles) ----
    if (t < NN * ED) el[t] = e[t];
    __syncthreads();

    if (t < 400) {
        int nn = t / 20, mm = t - (t / 20) * 20;
        float d = 0.f;
        #pragma unroll
        for (int j = 0; j < ED; ++j) d += el[nn * ED + j] * el[mm * ED + j];
        sA[t] = fmaxf(d, 0.f);
    }
    #pragma unroll
    for (int idx = t; idx < 1280; idx += THREADS) {
        int sel = idx >= 640;
        int rem = sel ? idx - 640 : idx;
        int c = rem >> 3, i = rem & 7;
        int n = c >> 2, ro = c & 3;
        float v = 0.f;
        if (ro < 2) {
            int o = 2 + ro;
            #pragma unroll
            for (int d = 0; d < ED; ++d) v += el[n * ED + d] * gate_w[d * 80 + sel * 40 + i * 4 + o];
        } else {
            int o = ro - 2;
            #pragma unroll
            for (int d = 0; d < ED; ++d) v += el[n * ED + d] * upd_w[d * 40 + sel * 20 + i * 2 + o];
        }
        (sel ? wagg : wself)[rem] = v;
    }
    if (t < NC) {
        int n = t >> 2, ro = t & 3;
        float b = 0.f;
        #pragma unroll
        for (int d = 0; d < ED; ++d)
            b += el[n * ED + d] * (ro < 2 ? gate_b[d * 4 + 2 + ro] : upd_b[d * 2 + ro - 2]);
        sbias[t] = b;
    }
    __syncthreads();

    if (t < NN) {
        float mx = -1e30f;
        for (int m = 0; m < NN; ++m) mx = fmaxf(mx, sA[t * 20 + m]);
        float ex[NN]; float sum = 0.f;
        for (int m = 0; m < NN; ++m) { ex[m] = __expf(sA[t * 20 + m] - mx); sum += ex[m]; }
        float inv = 1.f / sum;
        for (int m = 0; m < NN; ++m) sA[t * 20 + m] = ex[m] * inv;
    }
    __syncthreads();

    {
        half8* frag = (half8*)fragmem;
        for (int tile = w; tile < NKT * NNT; tile += 8) {
            int kt = tile / 5, nt = tile - kt * 5;
            int cc = nt * 16 + (l & 15);
            int nn = cc >> 2;
            int mm = kt * 4 + (l >> 4);
            float anm = sA[nn * 20 + mm];
            float4 wg0 = *(const float4*)&wagg[cc * 8];
            float4 wg1 = *(const float4*)&wagg[cc * 8 + 4];
            float v0 = anm * wg0.x, v1 = anm * wg0.y, v2 = anm * wg0.z, v3 = anm * wg0.w;
            float v4 = anm * wg1.x, v5 = anm * wg1.y, v6 = anm * wg1.z, v7 = anm * wg1.w;
            if (nn == mm) {
                float4 ws0 = *(const float4*)&wself[cc * 8];
                float4 ws1 = *(const float4*)&wself[cc * 8 + 4];
                v0 += ws0.x; v1 += ws0.y; v2 += ws0.z; v3 += ws0.w;
                v4 += ws1.x; v5 += ws1.y; v6 += ws1.z; v7 += ws1.w;
            }
            half8 hv;
            hv[0] = (_Float16)v0; hv[1] = (_Float16)v1; hv[2] = (_Float16)v2; hv[3] = (_Float16)v3;
            hv[4] = (_Float16)v4; hv[5] = (_Float16)v5; hv[6] = (_Float16)v6; hv[7] = (_Float16)v7;
            frag[tile * 64 + l] = hv;
        }
    }
    __syncthreads();

    const half8* frag = (const half8*)fragmem;
    const float lw0 = lin_w[0], lw1 = lin_w[1], lb = lin_b[0];
    const int ro = l & 3;
    const bool isR = ro < 2;
    const float myw = (ro & 1) ? lw1 : lw0;

    // ---- burst B issued NOW: latency hides under tile A's MFMA+epilogue ----
    float4 Ba0 = *(const float4*)(xpB);       float4 Bb0 = *(const float4*)(xpB + 4);
    float4 Ba1 = *(const float4*)(xpB + 32);  float4 Bb1 = *(const float4*)(xpB + 36);
    float4 Ba2 = *(const float4*)(xpB + 64);  float4 Bb2 = *(const float4*)(xpB + 68);
    float4 Ba3 = *(const float4*)(xpB + 96);  float4 Bb3 = *(const float4*)(xpB + 100);
    float4 Ba4 = *(const float4*)(xpB + 128); float4 Bb4 = *(const float4*)(xpB + 132);

    #define STEP(XA, XB, KT, ACC)                                                   \
    {                                                                               \
        half8 a = cvt8(XA, XB);                                                     \
        _Pragma("unroll")                                                           \
        for (int nt = 0; nt < NNT; ++nt) {                                          \
            half8 bh = frag[((KT) * NNT + nt) * 64 + l];                            \
            ACC[nt] = __builtin_amdgcn_mfma_f32_16x16x32_f16(a, bh, ACC[nt], 0, 0, 0); \
        }                                                                           \
    }

    #define EPILOGUE(ACC, ROW0)                                                     \
    {                                                                               \
        const size_t rowb = (ROW0) + ((l >> 4) << 2) + ro;                          \
        _Pragma("unroll")                                                           \
        for (int nt = 0; nt < NNT; ++nt) {                                          \
            const int n = nt * 4 + ((l & 15) >> 2);                                 \
            float ysel = 0.f;                                                       \
            _Pragma("unroll")                                                       \
            for (int q = 0; q < 4; ++q) {                                           \
                float pre = ACC[nt][q];                                             \
                float term;                                                         \
                if (isR) term = __builtin_amdgcn_rcpf(1.f + __expf(pre));           \
                else     term = 1.f - 2.f * __builtin_amdgcn_rcpf(__expf(2.f * pre) + 1.f); \
                float other = dpp_xor2(term);                                       \
                float h = term * other;                                             \
                float s = fmaxf(h, 0.f) * myw;                                      \
                float yq = s + dpp_xor1(s) + lb;                                    \
                if (q == ro) ysel = yq;                                             \
            }                                                                       \
            y[rowb * NN + n] = ysel;                                                \
        }                                                                           \
    }

    // ---- tile A ----
    {
        f32x4 accA[NNT];
        #pragma unroll
        for (int nt = 0; nt < NNT; ++nt) {
            float b = sbias[nt * 16 + (l & 15)];
            accA[nt] = (f32x4){b, b, b, b};
        }
        STEP(Aa0, Ab0, 0, accA)
        STEP(Aa1, Ab1, 1, accA)
        STEP(Aa2, Ab2, 2, accA)
        STEP(Aa3, Ab3, 3, accA)
        STEP(Aa4, Ab4, 4, accA)
        EPILOGUE(accA, rowA)
    }

    // ---- tile B ----
    {
        f32x4 accB[NNT];
        #pragma unroll
        for (int nt = 0; nt < NNT; ++nt) {
            float b = sbias[nt * 16 + (l & 15)];
            accB[nt] = (f32x4){b, b, b, b};
        }
        STEP(Ba0, Bb0, 0, accB)
        STEP(Ba1, Bb1, 1, accB)
        STEP(Ba2, Bb2, 2, accB)
        STEP(Ba3, Bb3, 3, accB)
        STEP(Ba4, Bb4, 4, accB)
        EPILOGUE(accB, rowB)
    }
    #undef STEP
    #undef EPILOGUE
}

extern "C" void kernel_launch(void* const* d_in, const int* in_sizes, int n_in,
                              void* d_out, int out_size, void* d_ws, size_t ws_size,
                              hipStream_t stream) {
    const float* x      = (const float*)d_in[0];
    const float* e      = (const float*)d_in[1];
    const float* gate_w = (const float*)d_in[2];
    const float* gate_b = (const float*)d_in[3];
    const float* upd_w  = (const float*)d_in[4];
    const float* upd_b  = (const float*)d_in[5];
    const float* lin_w  = (const float*)d_in[6];
    const float* lin_b  = (const float*)d_in[7];
    float* y = (float*)d_out;

    const int Bn = in_sizes[0] / XROW;                     // 131072
    const int nblocks = Bn / (ROWS_PER_BLOCK * TPB);       // 512

    rgcn_fused<<<nblocks, THREADS, 0, stream>>>(x, e, gate_w, gate_b,
                                                upd_w, upd_b, lin_w, lin_b, y);
}